// Round 1
// baseline (847.766 us; speedup 1.0000x reference)
//
#include <hip/hip_runtime.h>

#define D 256
#define H 128
#define CHUNK 32
#define PAD_LD 260   // 256 + 4 floats: breaks bank aliasing to 2-way (free), keeps 16B alignment (260*4=1040=65*16)

typedef __attribute__((ext_vector_type(8))) short bf16x8;
typedef __attribute__((ext_vector_type(4))) float f32x4;

__device__ __forceinline__ short f2bf(float f) {
    // RNE float->bf16 (no NaN handling needed: inputs are finite)
    union { float f; unsigned u; } v; v.f = f;
    unsigned r = v.u + 0x7FFFu + ((v.u >> 16) & 1u);
    return (short)(r >> 16);
}

__device__ __forceinline__ float fast_tanh(float a) {
    // tanh(a) = (e^{2a}-1)/(e^{2a}+1); |a| <= ~4 here so no overflow
    float t = __expf(2.0f * a);
    return (t - 1.0f) / (t + 1.0f);
}

__global__ __launch_bounds__(256)
void attn_pool_kernel(const float* __restrict__ x, const int* __restrict__ ids,
                      const float* __restrict__ W1, const float* __restrict__ b1,
                      const float* __restrict__ W2, const float* __restrict__ b2,
                      float* __restrict__ ctx_out, float* __restrict__ attn_out,
                      int N)
{
    const int seg  = blockIdx.x;
    const int tid  = threadIdx.x;
    const int lane = tid & 63;
    const int wave = tid >> 6;
    const int q    = lane >> 4;   // quad within wave
    const int ln   = lane & 15;

    __shared__ float xs[CHUNK][PAD_LD];  // fp32 x chunk, reused for MFMA A-frags and context accumulation
    __shared__ float zpart[CHUNK];       // per-row logit partial sums

    // --- segment bounds: ids is sorted, binary search (uniform across block -> scalar path) ---
    int lo = 0, hi = N;
    while (lo < hi) { int mid = (lo + hi) >> 1; if (ids[mid] < seg) lo = mid + 1; else hi = mid; }
    const int start = lo;
    hi = N;
    while (lo < hi) { int mid = (lo + hi) >> 1; if (ids[mid] < seg + 1) lo = mid + 1; else hi = mid; }
    const int end = lo;
    const int len = end - start;

    if (len == 0) {            // empty segment: context = 0, no tokens
        ctx_out[seg * D + tid] = 0.0f;
        return;
    }

    // --- preload W1 B-fragments (bf16) into registers: wave owns cols [32w, 32w+32) ---
    const int c0 = wave * 32 + ln;   // nt=0 column
    const int c1 = c0 + 16;          // nt=1 column
    bf16x8 bfrag[2][8];
#pragma unroll
    for (int s = 0; s < 8; ++s) {
        const int kbase = s * 32 + q * 8;
        bf16x8 f0, f1;
#pragma unroll
        for (int j = 0; j < 8; ++j) {
            f0[j] = f2bf(W1[(kbase + j) * H + c0]);
            f1[j] = f2bf(W1[(kbase + j) * H + c1]);
        }
        bfrag[0][s] = f0; bfrag[1][s] = f1;
    }
    const float b1v0 = b1[c0], b1v1 = b1[c1];
    const float w2v0 = W2[c0], w2v1 = W2[c1];
    const float b2v  = b2[0];

    // --- online softmax state (m,l redundant per thread; c_acc: thread t owns context col t) ---
    float m_run = -__builtin_inff();
    float l_run = 0.0f;
    float c_acc = 0.0f;

    const float* xseg  = x + (size_t)start * D;
    float*       zglob = attn_out + start;   // park raw z here, normalize at the end

    const int nchunks = (len + CHUNK - 1) / CHUNK;
    for (int ch = 0; ch < nchunks; ++ch) {
        const int rbase = ch * CHUNK;
        const int valid = min(CHUNK, len - rbase);

        if (tid < CHUNK) zpart[tid] = 0.0f;
        // stage x chunk -> LDS (coalesced float4; zero-fill ragged rows)
#pragma unroll
        for (int it = 0; it < 8; ++it) {
            const int e   = it * 1024 + tid * 4;
            const int r   = e >> 8;
            const int col = e & 255;
            float4 v = make_float4(0.0f, 0.0f, 0.0f, 0.0f);
            if (r < valid) v = *(const float4*)(xseg + (size_t)(rbase + r) * D + col);
            *(float4*)&xs[r][col] = v;
        }
        __syncthreads();

        // --- h = x @ W1 via MFMA 16x16x32 bf16; wave computes 32 rows x its 32 cols ---
        f32x4 acc[2][2];
#pragma unroll
        for (int mt = 0; mt < 2; ++mt)
#pragma unroll
            for (int nt = 0; nt < 2; ++nt)
                acc[mt][nt] = (f32x4){0.0f, 0.0f, 0.0f, 0.0f};
#pragma unroll
        for (int s = 0; s < 8; ++s) {
            const int k0 = s * 32 + q * 8;
            const float* p0 = &xs[ln][k0];        // A rows 0..15
            const float* p1 = &xs[16 + ln][k0];   // A rows 16..31
            bf16x8 a0, a1;
#pragma unroll
            for (int j = 0; j < 8; ++j) { a0[j] = f2bf(p0[j]); a1[j] = f2bf(p1[j]); }
            acc[0][0] = __builtin_amdgcn_mfma_f32_16x16x32_bf16(a0, bfrag[0][s], acc[0][0], 0, 0, 0);
            acc[0][1] = __builtin_amdgcn_mfma_f32_16x16x32_bf16(a0, bfrag[1][s], acc[0][1], 0, 0, 0);
            acc[1][0] = __builtin_amdgcn_mfma_f32_16x16x32_bf16(a1, bfrag[0][s], acc[1][0], 0, 0, 0);
            acc[1][1] = __builtin_amdgcn_mfma_f32_16x16x32_bf16(a1, bfrag[1][s], acc[1][1], 0, 0, 0);
        }

        // --- layer 2: z = tanh(h+b1)@W2 (+b2 later); C/D layout: col=ln, row=q*4+r (+16*mt) ---
#pragma unroll
        for (int mt = 0; mt < 2; ++mt) {
            float v[4];
#pragma unroll
            for (int r = 0; r < 4; ++r) {
                const float h0 = fast_tanh(acc[mt][0][r] + b1v0);
                const float h1 = fast_tanh(acc[mt][1][r] + b1v1);
                v[r] = h0 * w2v0 + h1 * w2v1;
            }
#pragma unroll
            for (int off = 8; off >= 1; off >>= 1)
#pragma unroll
                for (int r = 0; r < 4; ++r)
                    v[r] += __shfl_xor(v[r], off, 16);
            if (ln == 0) {
#pragma unroll
                for (int r = 0; r < 4; ++r)
                    atomicAdd(&zpart[mt * 16 + q * 4 + r], v[r]);
            }
        }
        __syncthreads();

        // --- online softmax update (redundant per thread; identical fp results) ---
        float cmax = -__builtin_inff();
        for (int r = 0; r < valid; ++r) cmax = fmaxf(cmax, zpart[r]);
        cmax += b2v;
        const float new_m = fmaxf(m_run, cmax);
        const float alpha = __expf(m_run - new_m);   // exp(-inf)=0 on first chunk
        float lsum = 0.0f, csum = 0.0f;
        for (int r = 0; r < valid; ++r) {
            const float e = __expf(zpart[r] + b2v - new_m);
            lsum += e;
            csum += e * xs[r][tid];                  // thread t accumulates context col t
        }
        c_acc = c_acc * alpha + csum;
        l_run = l_run * alpha + lsum;
        m_run = new_m;

        if (tid < valid) zglob[rbase + tid] = zpart[tid] + b2v;  // park raw z
        __syncthreads();   // also orders zglob writes for the final pass
    }

    // --- epilogue: context and normalized attention weights ---
    const float inv = 1.0f / l_run;
    ctx_out[seg * D + tid] = c_acc * inv;
    for (int i = tid; i < len; i += 256) {
        const float zi = zglob[i];
        zglob[i] = __expf(zi - m_run) * inv;
    }
}

extern "C" void kernel_launch(void* const* d_in, const int* in_sizes, int n_in,
                              void* d_out, int out_size, void* d_ws, size_t ws_size,
                              hipStream_t stream) {
    const float* x   = (const float*)d_in[0];
    const int*   ids = (const int*)d_in[1];
    // d_in[2] = num_segments (device scalar) — derived from sizes instead
    const float* W1  = (const float*)d_in[3];
    const float* b1  = (const float*)d_in[4];
    const float* W2  = (const float*)d_in[5];
    const float* b2  = (const float*)d_in[6];

    const int N = in_sizes[0] / D;              // 524288
    const int S = (out_size - N) / D;           // 2048
    float* ctx  = (float*)d_out;                // [S, D]
    float* attn = (float*)d_out + (size_t)S * D; // [N, 1]

    attn_pool_kernel<<<S, 256, 0, stream>>>(x, ids, W1, b1, W2, b2, ctx, attn, N);
}

// Round 2
// 786.262 us; speedup vs baseline: 1.0782x; 1.0782x over previous
//
#include <hip/hip_runtime.h>

#define D 256
#define H 128
#define CHUNK 32
#define PADB 264   // bf16 row stride: 528 B/row, /4 = 132 ≡ 4 (mod 32) -> uniform bank sweep for b128 frag reads

typedef __attribute__((ext_vector_type(8))) short bf16x8;
typedef __attribute__((ext_vector_type(4))) float f32x4;

__device__ __forceinline__ short f2bf(float f) {
    // RNE float->bf16 (inputs finite)
    union { float f; unsigned u; } v; v.f = f;
    unsigned r = v.u + 0x7FFFu + ((v.u >> 16) & 1u);
    return (short)(r >> 16);
}

__device__ __forceinline__ float fast_tanh(float a) {
    float t = __expf(2.0f * a);
    return (t - 1.0f) / (t + 1.0f);
}

__global__ __launch_bounds__(256, 4)
void attn_pool_kernel(const float* __restrict__ x, const int* __restrict__ ids,
                      const float* __restrict__ W1, const float* __restrict__ b1,
                      const float* __restrict__ W2, const float* __restrict__ b2,
                      float* __restrict__ ctx_out, float* __restrict__ attn_out,
                      int N)
{
    const int seg  = blockIdx.x;
    const int tid  = threadIdx.x;
    const int lane = tid & 63;
    const int wave = tid >> 6;
    const int q    = lane >> 4;
    const int ln   = lane & 15;

    __shared__ short xs_bf[CHUNK][PADB];   // bf16 x chunk (MFMA A operand)
    __shared__ float zw[4][CHUNK];         // per-wave layer-2 partials (no atomics)
    __shared__ float ez[CHUNK];            // per-row softmax weights for current chunk
    __shared__ float bc[2];                // {new_m, lsum}
    __shared__ float ctxbuf[4][64][4];     // epilogue cross-wave context reduce

    // --- segment bounds (ids sorted; block-uniform binary search) ---
    int lo = 0, hi = N;
    while (lo < hi) { int mid = (lo + hi) >> 1; if (ids[mid] < seg) lo = mid + 1; else hi = mid; }
    const int start = lo;
    hi = N;
    while (lo < hi) { int mid = (lo + hi) >> 1; if (ids[mid] < seg + 1) lo = mid + 1; else hi = mid; }
    const int len = lo - start;

    if (len == 0) {
        ctx_out[seg * D + tid] = 0.0f;
        return;
    }

    // --- preload W1 B-fragments (bf16): wave owns H-cols [32w, 32w+32) ---
    const int c0 = wave * 32 + ln;
    const int c1 = c0 + 16;
    bf16x8 bfrag[2][8];
#pragma unroll
    for (int s = 0; s < 8; ++s) {
        const int kbase = s * 32 + q * 8;
        bf16x8 f0, f1;
#pragma unroll
        for (int j = 0; j < 8; ++j) {
            f0[j] = f2bf(W1[(kbase + j) * H + c0]);
            f1[j] = f2bf(W1[(kbase + j) * H + c1]);
        }
        bfrag[0][s] = f0; bfrag[1][s] = f1;
    }
    const float b1v0 = b1[c0], b1v1 = b1[c1];
    const float w2v0 = W2[c0], w2v1 = W2[c1];
    const float b2v  = b2[0];

    // --- online softmax state; c_acc: thread owns 4 ctx cols x 8 row-groups ---
    float  m_run = -__builtin_inff();
    float  l_run = 0.0f;
    float4 c_acc = make_float4(0.0f, 0.0f, 0.0f, 0.0f);

    const float* xseg  = x + (size_t)start * D;
    float*       zglob = attn_out + start;   // park raw z; normalize at end

    const int sr = wave;             // row offset within each 4-row group
    const int sc = (tid & 63) * 4;   // column group

    const int nchunks = (len + CHUNK - 1) / CHUNK;
    for (int ch = 0; ch < nchunks; ++ch) {
        const int rbase = ch * CHUNK;
        const int valid = min(CHUNK, len - rbase);
        const float* gsrc = xseg + (size_t)rbase * D;

        // --- stage x chunk -> LDS as bf16 (coalesced float4 in, short4 out) ---
#pragma unroll
        for (int it = 0; it < 8; ++it) {
            const int r = it * 4 + sr;
            float4 v = make_float4(0.0f, 0.0f, 0.0f, 0.0f);
            if (r < valid) v = *(const float4*)(gsrc + (size_t)r * D + sc);
            short4 b;
            b.x = f2bf(v.x); b.y = f2bf(v.y); b.z = f2bf(v.z); b.w = f2bf(v.w);
            *(short4*)&xs_bf[r][sc] = b;
        }
        __syncthreads();

        // --- h = x @ W1 via MFMA 16x16x32 bf16 (A-frags: direct ds_read_b128) ---
        f32x4 acc[2][2];
#pragma unroll
        for (int mt = 0; mt < 2; ++mt)
#pragma unroll
            for (int nt = 0; nt < 2; ++nt)
                acc[mt][nt] = (f32x4){0.0f, 0.0f, 0.0f, 0.0f};
        const short* a0p = &xs_bf[ln][q * 8];
        const short* a1p = &xs_bf[16 + ln][q * 8];
#pragma unroll
        for (int s = 0; s < 8; ++s) {
            const bf16x8 a0 = *(const bf16x8*)(a0p + s * 32);
            const bf16x8 a1 = *(const bf16x8*)(a1p + s * 32);
            acc[0][0] = __builtin_amdgcn_mfma_f32_16x16x32_bf16(a0, bfrag[0][s], acc[0][0], 0, 0, 0);
            acc[0][1] = __builtin_amdgcn_mfma_f32_16x16x32_bf16(a0, bfrag[1][s], acc[0][1], 0, 0, 0);
            acc[1][0] = __builtin_amdgcn_mfma_f32_16x16x32_bf16(a1, bfrag[0][s], acc[1][0], 0, 0, 0);
            acc[1][1] = __builtin_amdgcn_mfma_f32_16x16x32_bf16(a1, bfrag[1][s], acc[1][1], 0, 0, 0);
        }

        // --- layer 2: tanh(h+b1)@W2; C/D layout col=ln, row=q*4+r (+16*mt) ---
#pragma unroll
        for (int mt = 0; mt < 2; ++mt) {
            float v[4];
#pragma unroll
            for (int r = 0; r < 4; ++r) {
                const float h0 = fast_tanh(acc[mt][0][r] + b1v0);
                const float h1 = fast_tanh(acc[mt][1][r] + b1v1);
                v[r] = h0 * w2v0 + h1 * w2v1;
            }
#pragma unroll
            for (int off = 8; off >= 1; off >>= 1)
#pragma unroll
                for (int r = 0; r < 4; ++r)
                    v[r] += __shfl_xor(v[r], off, 16);
            if (ln == 0) {
#pragma unroll
                for (int r = 0; r < 4; ++r)
                    zw[wave][mt * 16 + q * 4 + r] = v[r];
            }
        }
        __syncthreads();

        // --- softmax bookkeeping: threads 0..31 (wave 0) only ---
        if (tid < CHUNK) {
            const float zz = zw[0][tid] + zw[1][tid] + zw[2][tid] + zw[3][tid] + b2v;
            float zm = (tid < valid) ? zz : -__builtin_inff();
            float mx = zm;
#pragma unroll
            for (int off = 16; off >= 1; off >>= 1)
                mx = fmaxf(mx, __shfl_xor(mx, off, 32));
            const float nm = fmaxf(m_run, mx);
            const float e  = (tid < valid) ? __expf(zm - nm) : 0.0f;
            ez[tid] = e;
            float ls = e;
#pragma unroll
            for (int off = 16; off >= 1; off >>= 1)
                ls += __shfl_xor(ls, off, 32);
            if (tid == 0) { bc[0] = nm; bc[1] = ls; }
            if (tid < valid) zglob[rbase + tid] = zz;
        }
        __syncthreads();

        // --- context update: reload x (L1/L2-hit) and FMA with e; rescale by alpha ---
        const float nm    = bc[0];
        const float ls    = bc[1];
        const float alpha = __expf(m_run - nm);   // 0 on first chunk
        m_run = nm;
        l_run = l_run * alpha + ls;
        c_acc.x *= alpha; c_acc.y *= alpha; c_acc.z *= alpha; c_acc.w *= alpha;
#pragma unroll
        for (int it = 0; it < 8; ++it) {
            const int r = it * 4 + sr;
            if (r < valid) {
                const float  e = ez[r];           // wave-uniform broadcast read
                const float4 v = *(const float4*)(gsrc + (size_t)r * D + sc);
                c_acc.x += e * v.x; c_acc.y += e * v.y;
                c_acc.z += e * v.z; c_acc.w += e * v.w;
            }
        }
        __syncthreads();   // xs_bf/zw/ez free for next chunk
    }

    // --- epilogue: cross-wave context reduce + attention normalize ---
    const float inv = 1.0f / l_run;
    ctxbuf[sr][tid & 63][0] = c_acc.x * inv;
    ctxbuf[sr][tid & 63][1] = c_acc.y * inv;
    ctxbuf[sr][tid & 63][2] = c_acc.z * inv;
    ctxbuf[sr][tid & 63][3] = c_acc.w * inv;
    __syncthreads();
    if (tid < 64) {
        float4 s;
        s.x = ctxbuf[0][tid][0] + ctxbuf[1][tid][0] + ctxbuf[2][tid][0] + ctxbuf[3][tid][0];
        s.y = ctxbuf[0][tid][1] + ctxbuf[1][tid][1] + ctxbuf[2][tid][1] + ctxbuf[3][tid][1];
        s.z = ctxbuf[0][tid][2] + ctxbuf[1][tid][2] + ctxbuf[2][tid][2] + ctxbuf[3][tid][2];
        s.w = ctxbuf[0][tid][3] + ctxbuf[1][tid][3] + ctxbuf[2][tid][3] + ctxbuf[3][tid][3];
        *(float4*)&ctx_out[seg * D + tid * 4] = s;
    }
    for (int i = tid; i < len; i += 256) {
        zglob[i] = __expf(zglob[i] - m_run) * inv;
    }
}

extern "C" void kernel_launch(void* const* d_in, const int* in_sizes, int n_in,
                              void* d_out, int out_size, void* d_ws, size_t ws_size,
                              hipStream_t stream) {
    const float* x   = (const float*)d_in[0];
    const int*   ids = (const int*)d_in[1];
    const float* W1  = (const float*)d_in[3];
    const float* b1  = (const float*)d_in[4];
    const float* W2  = (const float*)d_in[5];
    const float* b2  = (const float*)d_in[6];

    const int N = in_sizes[0] / D;               // 524288
    const int S = (out_size - N) / D;            // 2048
    float* ctx  = (float*)d_out;                 // [S, D]
    float* attn = (float*)d_out + (size_t)S * D; // [N, 1]

    attn_pool_kernel<<<S, 256, 0, stream>>>(x, ids, W1, b1, W2, b2, ctx, attn, N);
}